// Round 1
// baseline (815.204 us; speedup 1.0000x reference)
//
#include <hip/hip_runtime.h>

// SolveSchedulingCvxpyLayer: batched FISTA on the dual of a ramp-constrained QP.
//   d = d2g + 1; p = dg - d2g*z0 - mu
//   repeat 4000x: nu <- soft(y + alpha*D(-(p+D^T y)/d), alpha*0.5), FISTA momentum
//   out = -(p + D^T nu)/d
// Mapping: one wave64 per batch item, 2 consecutive elements per lane.
// Cross-lane stencil via 2 shuffles/iteration. nu[127] (lane63 hi) does not
// exist -> its soft-threshold is +inf so it stays exactly 0.

#define N_HOR   128
#define N_ITERS 4000

__global__ __launch_bounds__(256) void fista_wave_kernel(
    const float* __restrict__ z0, const float* __restrict__ mu,
    const float* __restrict__ dg, const float* __restrict__ d2g,
    float* __restrict__ out, int B)
{
    const int wave = blockIdx.x * (blockDim.x >> 6) + (threadIdx.x >> 6);
    const int lane = threadIdx.x & 63;
    if (wave >= B) return;

    const size_t base = (size_t)wave * N_HOR + 2 * (size_t)lane;
    const float2 vz0  = *(const float2*)(z0  + base);
    const float2 vmu  = *(const float2*)(mu  + base);
    const float2 vdg  = *(const float2*)(dg  + base);
    const float2 vd2g = *(const float2*)(d2g + base);

    const float d_lo = vd2g.x + 1.0f;
    const float d_hi = vd2g.y + 1.0f;
    const float p_lo = vdg.x - vd2g.x * vz0.x - vmu.x;
    const float p_hi = vdg.y - vd2g.y * vz0.y - vmu.y;
    const float invd_lo = 1.0f / d_lo;   // exact divide, once
    const float invd_hi = 1.0f / d_hi;

    // alpha = min(d)/4 over the 128 entries: local min + wave butterfly
    float mn = fminf(d_lo, d_hi);
    #pragma unroll
    for (int off = 32; off > 0; off >>= 1)
        mn = fminf(mn, __shfl_xor(mn, off, 64));
    const float alpha  = 0.25f * mn;
    const float thr    = alpha * 0.5f;                       // alpha * c_ramp
    const float thr_hi = (lane == 63) ? __builtin_inff() : thr;  // kill nu[127]

    float nu_lo = 0.0f, nu_hi = 0.0f;
    float y_lo  = 0.0f, y_hi  = 0.0f;
    float t = 1.0f;

    for (int k = 0; k < N_ITERS; ++k) {
        // w = p + D^T y ; z = -w / d
        float ym1 = __shfl_up(y_hi, 1, 64);      // y[2l-1] from lane l-1
        ym1 = (lane == 0) ? 0.0f : ym1;
        const float zl = -(p_lo + y_lo - ym1) * invd_lo;
        const float zh = -(p_hi + y_hi - y_lo) * invd_hi;
        // g = D(z): g[i] = z[i] - z[i+1]
        const float zp1 = __shfl_down(zl, 1, 64);   // z[2l+2] from lane l+1
        const float xl = fmaf(alpha, zl - zh,  y_lo);
        const float xh = fmaf(alpha, zh - zp1, y_hi);
        // soft-threshold
        const float sl = copysignf(fmaxf(fabsf(xl) - thr,    0.0f), xl);
        const float sh = copysignf(fmaxf(fabsf(xh) - thr_hi, 0.0f), xh);
        // FISTA momentum (beta sequence is data-independent; approx sqrt/rcp ok)
        const float tn   = 0.5f * (1.0f + __builtin_amdgcn_sqrtf(fmaf(4.0f * t, t, 1.0f)));
        const float beta = (t - 1.0f) * __builtin_amdgcn_rcpf(tn);
        t = tn;
        y_lo = fmaf(beta, sl - nu_lo, sl);
        y_hi = fmaf(beta, sh - nu_hi, sh);
        nu_lo = sl; nu_hi = sh;
    }

    // z_star = -(p + D^T nu)/d
    float nm1 = __shfl_up(nu_hi, 1, 64);
    nm1 = (lane == 0) ? 0.0f : nm1;
    const float zl = -(p_lo + nu_lo - nm1) * invd_lo;
    const float zh = -(p_hi + nu_hi - nu_lo) * invd_hi;
    *(float2*)(out + base) = make_float2(zl, zh);
}

extern "C" void kernel_launch(void* const* d_in, const int* in_sizes, int n_in,
                              void* d_out, int out_size, void* d_ws, size_t ws_size,
                              hipStream_t stream) {
    const float* z0  = (const float*)d_in[0];
    const float* mu  = (const float*)d_in[1];
    const float* dg  = (const float*)d_in[2];
    const float* d2g = (const float*)d_in[3];
    float* out = (float*)d_out;
    const int B = in_sizes[0] / N_HOR;          // 4096

    const int waves_per_block = 4;              // 256 threads
    const int grid = (B + waves_per_block - 1) / waves_per_block;
    fista_wave_kernel<<<grid, 256, 0, stream>>>(z0, mu, dg, d2g, out, B);
}

// Round 2
// 669.370 us; speedup vs baseline: 1.2179x; 1.2179x over previous
//
#include <hip/hip_runtime.h>

// SolveSchedulingCvxpyLayer: batched FISTA on the dual of a ramp-constrained QP.
//   d = d2g + 1; p = dg - d2g*z0 - mu;  q = -p/d (hoisted)
//   repeat 4000x: nu <- soft(y + alpha*D(z(y)), alpha*0.5), FISTA momentum
//   z(y)_i = q_i + (y_{i-1} - y_i)/d_i   (dual-difference form)
// Mapping: one wave64 per batch item, 2 consecutive elements per lane
// (lane l holds indices 2l, 2l+1). Cross-lane stencil via DPP wave shifts:
//   wave_shr:1 (0x138) -> lane i reads lane i-1 (bound_ctrl: lane0 -> 0)
//   wave_shl:1 (0x130) -> lane i reads lane i+1 (bound_ctrl: lane63 -> 0)
// nu[127] (lane63 hi) does not exist -> its threshold is +inf, so
// soft(x) = x - med3(x,-inf,inf) = 0 exactly, forever.

#define N_HOR   128
#define N_ITERS 4000

__device__ __forceinline__ float dpp_shr1(float x) {  // lane i <- lane i-1, lane0 <- 0
    return __builtin_bit_cast(float,
        __builtin_amdgcn_update_dpp(0, __builtin_bit_cast(int, x), 0x138, 0xF, 0xF, true));
}
__device__ __forceinline__ float dpp_shl1(float x) {  // lane i <- lane i+1, lane63 <- 0
    return __builtin_bit_cast(float,
        __builtin_amdgcn_update_dpp(0, __builtin_bit_cast(int, x), 0x130, 0xF, 0xF, true));
}

__global__ __launch_bounds__(256) void fista_wave_kernel(
    const float* __restrict__ z0, const float* __restrict__ mu,
    const float* __restrict__ dg, const float* __restrict__ d2g,
    float* __restrict__ out, int B)
{
    const int wave = blockIdx.x * (blockDim.x >> 6) + (threadIdx.x >> 6);
    const int lane = threadIdx.x & 63;
    if (wave >= B) return;

    const size_t base = (size_t)wave * N_HOR + 2 * (size_t)lane;
    const float2 vz0  = *(const float2*)(z0  + base);
    const float2 vmu  = *(const float2*)(mu  + base);
    const float2 vdg  = *(const float2*)(dg  + base);
    const float2 vd2g = *(const float2*)(d2g + base);

    const float d_lo = vd2g.x + 1.0f;
    const float d_hi = vd2g.y + 1.0f;
    const float p_lo = vdg.x - vd2g.x * vz0.x - vmu.x;
    const float p_hi = vdg.y - vd2g.y * vz0.y - vmu.y;
    const float invd_lo = 1.0f / d_lo;     // exact divide, once
    const float invd_hi = 1.0f / d_hi;
    const float q_lo = -p_lo * invd_lo;    // z = q + (dy)*invd
    const float q_hi = -p_hi * invd_hi;

    // alpha = min(d)/4 over the 128 entries: local min + wave butterfly
    float mn = fminf(d_lo, d_hi);
    #pragma unroll
    for (int off = 32; off > 0; off >>= 1)
        mn = fminf(mn, __shfl_xor(mn, off, 64));
    const float alpha   = 0.25f * mn;
    const float thr     = alpha * 0.5f;                           // alpha * c_ramp
    const float thr_hi  = (lane == 63) ? __builtin_inff() : thr;  // kill nu[127]
    const float nthr    = -thr;
    const float nthr_hi = -thr_hi;

    float nu_lo = 0.0f, nu_hi = 0.0f;
    float y_lo  = 0.0f, y_hi  = 0.0f;
    float t = 1.0f;

    #pragma unroll 4
    for (int k = 0; k < N_ITERS; ++k) {
        // z = q + (y_{i-1} - y_i) * invd
        const float zl = fmaf(dpp_shr1(y_hi) - y_lo, invd_lo, q_lo);
        const float zh = fmaf(y_lo - y_hi,           invd_hi, q_hi);
        // x = y + alpha * (z_i - z_{i+1})
        const float xl = fmaf(alpha, zl - zh,           y_lo);
        const float xh = fmaf(alpha, zh - dpp_shl1(zl), y_hi);
        // soft-threshold: s = x - med3(x, -thr, thr)
        const float sl = xl - __builtin_amdgcn_fmed3f(xl, nthr,    thr);
        const float sh = xh - __builtin_amdgcn_fmed3f(xh, nthr_hi, thr_hi);
        // FISTA momentum (beta sequence data-independent; approx sqrt/rcp ok)
        const float tn   = fmaf(0.5f, __builtin_amdgcn_sqrtf(fmaf(4.0f * t, t, 1.0f)), 0.5f);
        const float beta = (t - 1.0f) * __builtin_amdgcn_rcpf(tn);
        t = tn;
        y_lo = fmaf(beta, sl - nu_lo, sl);
        y_hi = fmaf(beta, sh - nu_hi, sh);
        nu_lo = sl; nu_hi = sh;
    }

    // z_star = q + (nu_{i-1} - nu_i) * invd
    const float zl = fmaf(dpp_shr1(nu_hi) - nu_lo, invd_lo, q_lo);
    const float zh = fmaf(nu_lo - nu_hi,           invd_hi, q_hi);
    *(float2*)(out + base) = make_float2(zl, zh);
}

extern "C" void kernel_launch(void* const* d_in, const int* in_sizes, int n_in,
                              void* d_out, int out_size, void* d_ws, size_t ws_size,
                              hipStream_t stream) {
    const float* z0  = (const float*)d_in[0];
    const float* mu  = (const float*)d_in[1];
    const float* dg  = (const float*)d_in[2];
    const float* d2g = (const float*)d_in[3];
    float* out = (float*)d_out;
    const int B = in_sizes[0] / N_HOR;          // 4096

    const int waves_per_block = 4;              // 256 threads
    const int grid = (B + waves_per_block - 1) / waves_per_block;
    fista_wave_kernel<<<grid, 256, 0, stream>>>(z0, mu, dg, d2g, out, B);
}

// Round 3
// 462.405 us; speedup vs baseline: 1.7630x; 1.4476x over previous
//
#include <hip/hip_runtime.h>

// SolveSchedulingCvxpyLayer: batched FISTA on the dual of a ramp-constrained QP.
//   d = d2g + 1; p = dg - d2g*z0 - mu;  q = -p/d
//   iterate: x = (I - alpha*D*diag(1/d)*D^T) y + alpha*D q   (tridiagonal apply)
//            nu' = soft(x, alpha*0.5);  y = nu' + beta_k (nu' - nu)
//   out: z = q + diag(1/d) D^T nu
// Mapping: one wave64 per batch item, 2 consecutive elements per lane.
// Tridiagonal coefficients A,B,E,c precomputed per-lane; cross-lane neighbor
// terms via DPP wave shifts (1 VALU op, bound_ctrl gives 0 at the boundary).
// beta_k = k/(k+3) (Chambolle t_k=(k+2)/2) precomputed into d_ws each launch;
// the main loop reads it at a wave-uniform address -> s_load, zero VALU cost.
// nu[127] (lane63 hi) does not exist -> threshold +inf makes soft() pin it to 0.

#define N_HOR   128
#define N_ITERS 4000

typedef float float8 __attribute__((ext_vector_type(8)));

__global__ void beta_init_kernel(float* __restrict__ beta) {
    const int k = blockIdx.x * blockDim.x + threadIdx.x;
    if (k < N_ITERS) beta[k] = (float)k / (float)(k + 3);
}

__device__ __forceinline__ float dpp_shr1(float x) {  // lane i <- lane i-1, lane0 <- 0
    return __builtin_bit_cast(float,
        __builtin_amdgcn_update_dpp(0, __builtin_bit_cast(int, x), 0x138, 0xF, 0xF, true));
}
__device__ __forceinline__ float dpp_shl1(float x) {  // lane i <- lane i+1, lane63 <- 0
    return __builtin_bit_cast(float,
        __builtin_amdgcn_update_dpp(0, __builtin_bit_cast(int, x), 0x130, 0xF, 0xF, true));
}

__global__ __launch_bounds__(256) void fista_wave_kernel(
    const float* __restrict__ z0, const float* __restrict__ mu,
    const float* __restrict__ dg, const float* __restrict__ d2g,
    const float* __restrict__ beta_tab,
    float* __restrict__ out, int B)
{
    const int wave = blockIdx.x * (blockDim.x >> 6) + (threadIdx.x >> 6);
    const int lane = threadIdx.x & 63;
    if (wave >= B) return;

    const size_t base = (size_t)wave * N_HOR + 2 * (size_t)lane;
    const float2 vz0  = *(const float2*)(z0  + base);
    const float2 vmu  = *(const float2*)(mu  + base);
    const float2 vdg  = *(const float2*)(dg  + base);
    const float2 vd2g = *(const float2*)(d2g + base);

    const float d_lo = vd2g.x + 1.0f;
    const float d_hi = vd2g.y + 1.0f;
    const float p_lo = vdg.x - vd2g.x * vz0.x - vmu.x;
    const float p_hi = vdg.y - vd2g.y * vz0.y - vmu.y;
    const float invd_lo = 1.0f / d_lo;     // exact divide, once
    const float invd_hi = 1.0f / d_hi;
    const float q_lo = -p_lo * invd_lo;
    const float q_hi = -p_hi * invd_hi;

    // alpha = min(d)/4 over the 128 entries: local min + wave butterfly
    float mn = fminf(d_lo, d_hi);
    #pragma unroll
    for (int off = 32; off > 0; off >>= 1)
        mn = fminf(mn, __shfl_xor(mn, off, 64));
    const float alpha  = 0.25f * mn;
    const float thr    = alpha * 0.5f;                           // alpha * c_ramp
    const float thr_hi = (lane == 63) ? __builtin_inff() : thr;  // pin nu[127] to 0

    // Tridiagonal operator x = A*y_{i-1} + B*y_i + E*y_{i+1} + c
    const float invd_nx = dpp_shl1(invd_lo);   // invd_{2l+2}; lane63 -> 0 (kills E_hi)
    const float q_nx    = dpp_shl1(q_lo);
    const float ail = alpha * invd_lo;
    const float aih = alpha * invd_hi;
    const float ain = alpha * invd_nx;
    const float A_lo = ail, E_lo = aih, B_lo = 1.0f - (ail + aih);
    const float A_hi = aih, E_hi = ain, B_hi = 1.0f - (aih + ain);
    const float c_lo = alpha * (q_lo - q_hi);
    const float c_hi = alpha * (q_hi - q_nx);   // slot 127: value irrelevant (soft -> 0)

    float nu_lo = 0.0f, nu_hi = 0.0f;
    float y_lo  = 0.0f, y_hi  = 0.0f;

    for (int ko = 0; ko < N_ITERS / 8; ++ko) {
        const float8 bv = *(const float8*)(beta_tab + 8 * ko);   // uniform -> s_load_dwordx8
        #pragma unroll
        for (int j = 0; j < 8; ++j) {
            const float beta = bv[j];
            // x = A*y_{i-1} + B*y_i + E*y_{i+1} + c  (c seeds the fma chain)
            const float ym1 = dpp_shr1(y_hi);
            const float yp2 = dpp_shl1(y_lo);
            const float xl = fmaf(A_lo, ym1,  fmaf(B_lo, y_lo, fmaf(E_lo, y_hi, c_lo)));
            const float xh = fmaf(A_hi, y_lo, fmaf(B_hi, y_hi, fmaf(E_hi, yp2, c_hi)));
            // soft-threshold: s = x - med3(x, -thr, thr)   (neg modifier is free)
            const float sl = xl - __builtin_amdgcn_fmed3f(xl, -thr,    thr);
            const float sh = xh - __builtin_amdgcn_fmed3f(xh, -thr_hi, thr_hi);
            // momentum
            y_lo = fmaf(beta, sl - nu_lo, sl);
            y_hi = fmaf(beta, sh - nu_hi, sh);
            nu_lo = sl; nu_hi = sh;
        }
    }

    // z_star = q + (nu_{i-1} - nu_i) * invd
    const float zl = fmaf(dpp_shr1(nu_hi) - nu_lo, invd_lo, q_lo);
    const float zh = fmaf(nu_lo - nu_hi,           invd_hi, q_hi);
    *(float2*)(out + base) = make_float2(zl, zh);
}

extern "C" void kernel_launch(void* const* d_in, const int* in_sizes, int n_in,
                              void* d_out, int out_size, void* d_ws, size_t ws_size,
                              hipStream_t stream) {
    const float* z0  = (const float*)d_in[0];
    const float* mu  = (const float*)d_in[1];
    const float* dg  = (const float*)d_in[2];
    const float* d2g = (const float*)d_in[3];
    float* out = (float*)d_out;
    float* beta_tab = (float*)d_ws;            // 4000 floats, rebuilt every launch
    const int B = in_sizes[0] / N_HOR;         // 4096

    beta_init_kernel<<<(N_ITERS + 255) / 256, 256, 0, stream>>>(beta_tab);

    const int waves_per_block = 4;             // 256 threads
    const int grid = (B + waves_per_block - 1) / waves_per_block;
    fista_wave_kernel<<<grid, 256, 0, stream>>>(z0, mu, dg, d2g, beta_tab, out, B);
}

// Round 4
// 363.722 us; speedup vs baseline: 2.2413x; 1.2713x over previous
//
#include <hip/hip_runtime.h>

// SolveSchedulingCvxpyLayer: batched FISTA on the dual of a ramp-constrained QP.
//   d = d2g + 1; p = dg - d2g*z0 - mu;  q = -p/d
//   iterate: x = (I - alpha*D*diag(1/d)*D^T) y + alpha*D q   (tridiagonal apply)
//            nu' = soft(x, alpha*0.5);  y = nu' + beta_k (nu' - nu)
//   out: z = q + diag(1/d) D^T nu
// Mapping: one wave64 per batch item, elements (2l, 2l+1) in a packed VGPR
// pair -> VOP3P packed-FP32 math (v_pk_fma_f32 / v_pk_add_f32, 2 elems/instr).
// Tridiagonal per-element: x_i = A_i y_{i-1} + B_i y_i + E_i y_{i+1} + c_i with
//   A_i = a/d_i, E_i = a/d_{i+1}, B_i = 1 - A_i - E_i, c_i = a(q_i - q_{i+1}).
// Key identity: E_lo == A_hi == a/d_{2l+1}, so the in-lane cross term is ONE
// v_pk_fma with op_sel-swapped y (inline asm guarantees the op_sel fold).
// Neighbor terms via DPP wave shifts feeding scalar fma.
// beta_k = k/(k+3) precomputed into d_ws; wave-uniform s_load in the loop.
// nu[127] (lane63 hi) does not exist -> threshold +inf pins it to 0 via soft().

#define N_HOR   128
#define N_ITERS 4000

typedef float v2f    __attribute__((ext_vector_type(2)));
typedef float float8 __attribute__((ext_vector_type(8)));

__global__ void beta_init_kernel(float* __restrict__ beta) {
    const int k = blockIdx.x * blockDim.x + threadIdx.x;
    if (k < N_ITERS) beta[k] = (float)k / (float)(k + 3);
}

__device__ __forceinline__ float dpp_shr1(float x) {  // lane i <- lane i-1, lane0 <- 0
    return __builtin_bit_cast(float,
        __builtin_amdgcn_update_dpp(0, __builtin_bit_cast(int, x), 0x138, 0xF, 0xF, true));
}
__device__ __forceinline__ float dpp_shl1(float x) {  // lane i <- lane i+1, lane63 <- 0
    return __builtin_bit_cast(float,
        __builtin_amdgcn_update_dpp(0, __builtin_bit_cast(int, x), 0x130, 0xF, 0xF, true));
}

__global__ __launch_bounds__(256) void fista_wave_kernel(
    const float* __restrict__ z0, const float* __restrict__ mu,
    const float* __restrict__ dg, const float* __restrict__ d2g,
    const float* __restrict__ beta_tab,
    float* __restrict__ out, int B)
{
    const int wave = blockIdx.x * (blockDim.x >> 6) + (threadIdx.x >> 6);
    const int lane = threadIdx.x & 63;
    if (wave >= B) return;

    const size_t base = (size_t)wave * N_HOR + 2 * (size_t)lane;
    const float2 vz0  = *(const float2*)(z0  + base);
    const float2 vmu  = *(const float2*)(mu  + base);
    const float2 vdg  = *(const float2*)(dg  + base);
    const float2 vd2g = *(const float2*)(d2g + base);

    const float d_lo = vd2g.x + 1.0f;
    const float d_hi = vd2g.y + 1.0f;
    const float p_lo = vdg.x - vd2g.x * vz0.x - vmu.x;
    const float p_hi = vdg.y - vd2g.y * vz0.y - vmu.y;
    const float invd_lo = 1.0f / d_lo;     // exact divide, once
    const float invd_hi = 1.0f / d_hi;
    const float q_lo = -p_lo * invd_lo;
    const float q_hi = -p_hi * invd_hi;

    // alpha = min(d)/4 over the 128 entries: local min + wave butterfly
    float mn = fminf(d_lo, d_hi);
    #pragma unroll
    for (int off = 32; off > 0; off >>= 1)
        mn = fminf(mn, __shfl_xor(mn, off, 64));
    const float alpha  = 0.25f * mn;
    const float thr    = alpha * 0.5f;                           // alpha * c_ramp
    const float thr_hi = (lane == 63) ? __builtin_inff() : thr;  // pin nu[127] to 0

    // Tridiagonal coefficients
    const float invd_nx = dpp_shl1(invd_lo);   // invd_{2l+2}; lane63 -> 0 (E_hi = 0)
    const float q_nx    = dpp_shl1(q_lo);
    const float ail = alpha * invd_lo;         // A_lo
    const float aih = alpha * invd_hi;         // E_lo == A_hi
    const float ain = alpha * invd_nx;         // E_hi
    const v2f  Bpk = { 1.0f - (ail + aih), 1.0f - (aih + ain) };
    const v2f  cpk = { alpha * (q_lo - q_hi), alpha * (q_hi - q_nx) };
    const v2f  Gpk = { aih, aih };             // cross-term coefficient, both halves

    v2f nu = {0.0f, 0.0f};
    v2f y  = {0.0f, 0.0f};

    for (int ko = 0; ko < N_ITERS / 8; ++ko) {
        const float8 bv = *(const float8*)(beta_tab + 8 * ko);   // uniform -> s_load
        #pragma unroll
        for (int j = 0; j < 8; ++j) {
            const float beta = bv[j];
            const float ym1 = dpp_shr1(y.y);   // y_{2l-1}
            const float yp2 = dpp_shl1(y.x);   // y_{2l+2}
            // x = B ⊗ y + c   (one v_pk_fma)
            v2f x = __builtin_elementwise_fma(Bpk, y, cpk);
            // x += G ⊗ swap(y): lo += aih*y.hi, hi += aih*y.lo  (one v_pk_fma, op_sel)
            asm("v_pk_fma_f32 %0, %1, %2, %0 op_sel:[0,1,0] op_sel_hi:[1,0,1]"
                : "+v"(x) : "v"(Gpk), "v"(y));
            // neighbor terms (scalar fma, DPP-fed)
            x.x = fmaf(ail, ym1, x.x);
            x.y = fmaf(ain, yp2, x.y);
            // soft-threshold: s = x - med3(x,-t,t) = x + med3(-x,-t,t) (neg mods free)
            const v2f negm = { __builtin_amdgcn_fmed3f(-x.x, -thr,    thr),
                               __builtin_amdgcn_fmed3f(-x.y, -thr_hi, thr_hi) };
            const v2f s = x + negm;            // one v_pk_add
            // momentum
            const v2f t = s - nu;              // one v_pk_add (neg folded)
            y.x = fmaf(beta, t.x, s.x);
            y.y = fmaf(beta, t.y, s.y);
            nu = s;
        }
    }

    // z_star = q + (nu_{i-1} - nu_i) * invd
    const float zl = fmaf(dpp_shr1(nu.y) - nu.x, invd_lo, q_lo);
    const float zh = fmaf(nu.x - nu.y,           invd_hi, q_hi);
    *(float2*)(out + base) = make_float2(zl, zh);
}

extern "C" void kernel_launch(void* const* d_in, const int* in_sizes, int n_in,
                              void* d_out, int out_size, void* d_ws, size_t ws_size,
                              hipStream_t stream) {
    const float* z0  = (const float*)d_in[0];
    const float* mu  = (const float*)d_in[1];
    const float* dg  = (const float*)d_in[2];
    const float* d2g = (const float*)d_in[3];
    float* out = (float*)d_out;
    float* beta_tab = (float*)d_ws;            // 4000 floats, rebuilt every launch
    const int B = in_sizes[0] / N_HOR;         // 4096

    beta_init_kernel<<<(N_ITERS + 255) / 256, 256, 0, stream>>>(beta_tab);

    const int waves_per_block = 4;             // 256 threads
    const int grid = (B + waves_per_block - 1) / waves_per_block;
    fista_wave_kernel<<<grid, 256, 0, stream>>>(z0, mu, dg, d2g, beta_tab, out, B);
}